// Round 14
// baseline (115.426 us; speedup 1.0000x reference)
//
#include <hip/hip_runtime.h>
#include <hip/hip_bf16.h>

#define HW 16384
// (1/sqrt(32)) * log2(e): folded into q weights so exp(S) == exp2(S')
#define QSCALE (0.17677669529663687f * 1.4426950408889634f)

typedef __attribute__((ext_vector_type(8))) short short8;
typedef __attribute__((ext_vector_type(4))) float floatx4;
typedef __attribute__((ext_vector_type(16))) float floatx16;

// HW packed convert: lo = bf16(a), hi = bf16(b)  (RNE on gfx950)
__device__ inline unsigned cvt_pk_bf16(float a, float b) {
  unsigned r;
  asm("v_cvt_pk_bf16_f32 %0, %1, %2" : "=v"(r) : "v"(a), "v"(b));
  return r;
}
__device__ inline unsigned short f2bf(float a) {
  return (unsigned short)(cvt_pk_bf16(a, 0.f) & 0xffff);
}
__device__ inline float bf2f(unsigned short u) {
  union { unsigned u; float f; } c;
  c.u = (unsigned)u << 16;
  return c.f;
}
// exchange: a.hi32lanes <-> b.lo32lanes (both registers updated)
__device__ inline void permlane32_swap(unsigned& a, unsigned& b) {
  asm("v_permlane32_swap_b32 %0, %1" : "+v"(a), "+v"(b));
}
// bare v_exp_f32 (no OCML over/underflow fixup; exact for |x| < 126)
__device__ inline float fast_exp2(float x) {
  return __builtin_amdgcn_exp2f(x);
}

// ---------------------------------------------------------------------------
// cast_wx: blocks 0..255 transpose x f32 [128][HW] -> x_t bf16 [HW][128];
// blocks 256..303 cast w_qkv f32 [384][128] -> bf16 (q rows scaled by QSCALE)
// ---------------------------------------------------------------------------
__global__ __launch_bounds__(256) void cast_wx(
    const float* __restrict__ w, const float* __restrict__ x,
    unsigned short* __restrict__ w_bf, unsigned short* __restrict__ x_t) {
  __shared__ float tile[128][65];
  const int t = threadIdx.x;
  if (blockIdx.x >= 256) {
    const int i4 = ((blockIdx.x - 256) * 256 + t) * 4;
    const int o = i4 >> 7;
    const float sc = (o < 128) ? QSCALE : 1.f;
    float4 v = *(const float4*)&w[i4];
    uint2 u = {cvt_pk_bf16(v.x * sc, v.y * sc), cvt_pk_bf16(v.z * sc, v.w * sc)};
    *(uint2*)&w_bf[i4] = u;
    return;
  }
  const int p0 = blockIdx.x * 64;
  #pragma unroll
  for (int i = 0; i < 32; ++i) {
    int idx = t + i * 256;
    int c = idx >> 6, p = idx & 63;
    tile[c][p] = x[c * HW + p0 + p];
  }
  __syncthreads();
  const int p = t >> 2, q = t & 3;
  unsigned u[16];
  #pragma unroll
  for (int i = 0; i < 16; ++i)
    u[i] = cvt_pk_bf16(tile[q * 32 + 2 * i][p], tile[q * 32 + 2 * i + 1][p]);
  unsigned short* dst = &x_t[(p0 + p) * 128 + q * 32];
  #pragma unroll
  for (int i = 0; i < 4; ++i) *(uint4*)&dst[i * 8] = *(const uint4*)&u[i * 4];
}

// ---------------------------------------------------------------------------
// gemm_qkv: MFMA bf16, one block = all 384 o-rows x 32-p slab.
// q -> q_t bf16 [bn][c][32] (QSCALE folded), k -> k_t, v -> v_bf [128][HW].
// Epilogue: per-block v row-sums -> part_v[block][128] (feeds SE mean).
// grid 512 (2 blocks/CU), block 512 (8 waves x 48 o-rows)
// ---------------------------------------------------------------------------
__global__ __launch_bounds__(512) void gemm_qkv(
    const unsigned short* __restrict__ w_bf, const unsigned short* __restrict__ x_t,
    unsigned short* __restrict__ q_t, unsigned short* __restrict__ k_t,
    unsigned short* __restrict__ v_bf, float* __restrict__ part_v) {
  const int wave = threadIdx.x >> 6, lane = threadIdx.x & 63;
  const int lr = lane & 15, g = lane >> 4;
  const int p0 = blockIdx.x * 32;
  const int ow = wave * 48;
  const floatx4 zero = {0.f, 0.f, 0.f, 0.f};

  short8 a[3][4];
  #pragma unroll
  for (int mf = 0; mf < 3; ++mf)
    #pragma unroll
    for (int kk = 0; kk < 4; ++kk)
      a[mf][kk] = *(const short8*)&w_bf[(ow + mf * 16 + lr) * 128 + kk * 32 + g * 8];

  floatx4 acc[3][2];
  #pragma unroll
  for (int mf = 0; mf < 3; ++mf)
    #pragma unroll
    for (int nf = 0; nf < 2; ++nf) acc[mf][nf] = zero;

  #pragma unroll
  for (int kk = 0; kk < 4; ++kk) {
    #pragma unroll
    for (int nf = 0; nf < 2; ++nf) {
      short8 b = *(const short8*)&x_t[(p0 + nf * 16 + lr) * 128 + kk * 32 + g * 8];
      #pragma unroll
      for (int mf = 0; mf < 3; ++mf)
        acc[mf][nf] = __builtin_amdgcn_mfma_f32_16x16x32_bf16(a[mf][kk], b, acc[mf][nf], 0, 0, 0);
    }
  }

  float vsum[3][4];
  #pragma unroll
  for (int mf = 0; mf < 3; ++mf)
    #pragma unroll
    for (int rr = 0; rr < 4; ++rr) vsum[mf][rr] = 0.f;

  #pragma unroll
  for (int mf = 0; mf < 3; ++mf) {
    const int ob = ow + mf * 16;
    #pragma unroll
    for (int nf = 0; nf < 2; ++nf) {
      const int p = p0 + nf * 16 + lr;
      const int c = p & 2047, nn = p >> 11;
      floatx4 r = acc[mf][nf];
      if (ob < 128) {
        const int bh = ob >> 5, d0 = (ob & 31) + g * 4;
        uint2 u = {cvt_pk_bf16(r[0], r[1]), cvt_pk_bf16(r[2], r[3])};
        *(uint2*)&q_t[((bh * 8 + nn) * 2048 + c) * 32 + d0] = u;
      } else if (ob < 256) {
        const int oo = ob - 128, bh = oo >> 5, d0 = (oo & 31) + g * 4;
        uint2 u = {cvt_pk_bf16(r[0], r[1]), cvt_pk_bf16(r[2], r[3])};
        *(uint2*)&k_t[((bh * 8 + nn) * 2048 + c) * 32 + d0] = u;
      } else {
        const int d = ob - 256 + g * 4;
        #pragma unroll
        for (int rr = 0; rr < 4; ++rr) {
          v_bf[(d + rr) * HW + p] = f2bf(r[rr]);
          vsum[mf][rr] += r[rr];
        }
      }
    }
  }
  // v row-sum partials: reduce over the 16 p-lanes (lr), write per-block
  #pragma unroll
  for (int mf = 0; mf < 3; ++mf) {
    const int ob = ow + mf * 16;
    if (ob >= 256) {
      #pragma unroll
      for (int rr = 0; rr < 4; ++rr) {
        float vv = vsum[mf][rr];
        vv += __shfl_xor(vv, 1); vv += __shfl_xor(vv, 2);
        vv += __shfl_xor(vv, 4); vv += __shfl_xor(vv, 8);
        if (lr == 0)
          part_v[blockIdx.x * 128 + (ob - 256) + g * 4 + rr] = vv;
      }
    }
  }
}

// ---------------------------------------------------------------------------
// se_mlp: reduce part_v (512 planes) -> mean(v) = SE input; gate g;
// w_g = out_w * g (bf16).  (softmax rows sum to 1 => mean(attn_out)=mean(v))
// ---------------------------------------------------------------------------
__global__ __launch_bounds__(128) void se_mlp(
    const float* __restrict__ part_v, const float* __restrict__ w1,
    const float* __restrict__ b1, const float* __restrict__ w2,
    const float* __restrict__ b2, const float* __restrict__ out_w,
    unsigned short* __restrict__ w_g) {
  __shared__ float s_sh[128], s1_sh[32], g_sh[128];
  const int t = threadIdx.x;
  float a0 = 0.f;
  for (int b = 0; b < 512; ++b) a0 += part_v[b * 128 + t];
  s_sh[t] = a0 * (1.f / HW);
  __syncthreads();
  if (t < 32) {
    float a = b1[t];
    for (int c = 0; c < 128; ++c) a += w1[t * 128 + c] * s_sh[c];
    s1_sh[t] = a / (1.f + __expf(-a));
  }
  __syncthreads();
  {
    float a = b2[t];
    for (int i = 0; i < 32; ++i) a += w2[t * 32 + i] * s1_sh[i];
    g_sh[t] = 1.f / (1.f + __expf(-a));
  }
  __syncthreads();
  for (int o = 0; o < 128; ++o) w_g[o * 128 + t] = f2bf(out_w[o * 128 + t] * g_sh[t]);
}

// ---------------------------------------------------------------------------
// Pass A: Z partials via 32x32x16 MFMA, TWO independent e-tile chains +
// register-prefetched k loads, e split in 4 parts.
// grid 2048 flat (f&7 -> bn%8, XCD-pinned), block 256 (4 waves x 32 c)
// ---------------------------------------------------------------------------
__global__ __launch_bounds__(256, 4) void attn_stats_mfma(
    const unsigned short* __restrict__ q_t, const unsigned short* __restrict__ k_t,
    float* __restrict__ zpart) {
  const int wave = threadIdx.x >> 6, lane = threadIdx.x & 63;
  const int f = blockIdx.x;
  const int bn = ((f >> 7) & 3) * 8 + (f & 7);
  const int ct = (f >> 3) & 15;
  const int epart = f >> 9;  // 0..3
  const int l31 = lane & 31, h = lane >> 5;
  const int c0 = ct * 128 + wave * 32;
  const floatx16 z16 = {0.f,0.f,0.f,0.f,0.f,0.f,0.f,0.f,
                        0.f,0.f,0.f,0.f,0.f,0.f,0.f,0.f};

  const unsigned short* qp = &q_t[(bn * 2048 + c0 + l31) * 32 + h * 8];
  short8 aq0 = *(const short8*)qp;
  short8 aq1 = *(const short8*)(qp + 16);

  float z[16] = {};
  const unsigned short* kb = &k_t[(bn * 2048 + epart * 512 + l31) * 32 + h * 8];

  short8 b0a = *(const short8*)&kb[0];
  short8 b0b = *(const short8*)&kb[16];
  short8 b1a = *(const short8*)&kb[32 * 32];
  short8 b1b = *(const short8*)&kb[32 * 32 + 16];

  for (int e0 = 0; e0 < 512; e0 += 64) {
    // prefetch next 64-e pair (harmless overrun on last iteration)
    const unsigned short* nk = &kb[(e0 + 64) * 32];
    short8 nb0a = *(const short8*)&nk[0];
    short8 nb0b = *(const short8*)&nk[16];
    short8 nb1a = *(const short8*)&nk[32 * 32];
    short8 nb1b = *(const short8*)&nk[32 * 32 + 16];

    floatx16 s1 = __builtin_amdgcn_mfma_f32_32x32x16_bf16(aq0, b0a, z16, 0, 0, 0);
    s1 = __builtin_amdgcn_mfma_f32_32x32x16_bf16(aq1, b0b, s1, 0, 0, 0);
    floatx16 s2 = __builtin_amdgcn_mfma_f32_32x32x16_bf16(aq0, b1a, z16, 0, 0, 0);
    s2 = __builtin_amdgcn_mfma_f32_32x32x16_bf16(aq1, b1b, s2, 0, 0, 0);
    #pragma unroll
    for (int r = 0; r < 16; ++r) z[r] += fast_exp2(s1[r]) + fast_exp2(s2[r]);

    b0a = nb0a; b0b = nb0b; b1a = nb1a; b1b = nb1b;
  }
  #pragma unroll
  for (int r = 0; r < 16; ++r) {
    float v = z[r];
    v += __shfl_xor(v, 1); v += __shfl_xor(v, 2); v += __shfl_xor(v, 4);
    v += __shfl_xor(v, 8); v += __shfl_xor(v, 16);
    z[r] = v;
  }
  if (l31 == 0) {
    #pragma unroll
    for (int r = 0; r < 16; ++r)
      zpart[epart * 65536 + bn * 2048 + c0 + (r & 3) + 8 * (r >> 2) + 4 * h] = z[r];
  }
}

// ---------------------------------------------------------------------------
// vz = v / sum(4 z parts), bf16 [d][hw].  grid 1024, block 256, 8 elts/thread
// ---------------------------------------------------------------------------
__global__ __launch_bounds__(256) void vz_cast(
    const unsigned short* __restrict__ v_bf, const float* __restrict__ zpart,
    unsigned short* __restrict__ vz) {
  const int idx = (blockIdx.x * 256 + threadIdx.x) * 8;
  const int row = idx >> 14, p = idx & 16383;
  const int bh = row >> 5, nn = p >> 11, c = p & 2047;
  short8 v8 = *(const short8*)&v_bf[idx];
  const int zb = (bh * 8 + nn) * 2048 + c;
  float zs[8];
  #pragma unroll
  for (int i = 0; i < 8; ++i)
    zs[i] = __builtin_amdgcn_rcpf((zpart[zb + i] + zpart[65536 + zb + i]) +
                                  (zpart[131072 + zb + i] + zpart[196608 + zb + i]));
  unsigned u[4];
  #pragma unroll
  for (int i = 0; i < 4; ++i)
    u[i] = cvt_pk_bf16(bf2f((unsigned short)v8[2 * i]) * zs[2 * i],
                       bf2f((unsigned short)v8[2 * i + 1]) * zs[2 * i + 1]);
  uint4 o = {u[0], u[1], u[2], u[3]};
  *(uint4*)&vz[idx] = o;
}

// ---------------------------------------------------------------------------
// Pass B: PV via 32x32x16 MFMA. Wave owns TWO j-tiles (independent chains,
// shared aq/av loads) + register double-buffered prefetch; c split in 4.
// P handed QK->PV in-register via v_permlane32_swap. No LDS, no barriers.
// grid 1024 flat (f&7 -> bn%8, XCD-pinned), block 256.
// Output att_t bf16 transposed [hw][128], 4 c-part partials.
// ---------------------------------------------------------------------------
__global__ __launch_bounds__(256, 4) void attn_apply_mfma(
    const unsigned short* __restrict__ q_t, const unsigned short* __restrict__ k_t,
    const unsigned short* __restrict__ vz, unsigned short* __restrict__ att_t) {
  const int wave = threadIdx.x >> 6, lane = threadIdx.x & 63;
  const int f = blockIdx.x;
  const int bn = ((f >> 6) & 3) * 8 + (f & 7);
  const int jg = (f >> 3) & 7;
  const int cpart = f >> 8;  // 0..3
  const int bh = bn >> 3, nn = bn & 7;
  const int jA = jg * 256 + wave * 64;
  const int jB = jA + 32;
  const int l31 = lane & 31, h = lane >> 5;
  const floatx16 z16 = {0.f,0.f,0.f,0.f,0.f,0.f,0.f,0.f,
                        0.f,0.f,0.f,0.f,0.f,0.f,0.f,0.f};

  const unsigned short* kpA = &k_t[(bn * 2048 + jA + l31) * 32 + h * 8];
  const unsigned short* kpB = &k_t[(bn * 2048 + jB + l31) * 32 + h * 8];
  short8 bkA0 = *(const short8*)kpA, bkA1 = *(const short8*)(kpA + 16);
  short8 bkB0 = *(const short8*)kpB, bkB1 = *(const short8*)(kpB + 16);

  floatx16 accA = z16, accB = z16;
  const unsigned short* qb = &q_t[(bn * 2048 + cpart * 512 + l31) * 32 + h * 8];
  const unsigned short* vb = &vz[(bh * 32 + l31) * HW + nn * 2048 + cpart * 512 + h * 8];

  short8 aq0 = *(const short8*)&qb[0];
  short8 aq1 = *(const short8*)&qb[16];
  short8 av0 = *(const short8*)&vb[0];
  short8 av1 = *(const short8*)&vb[16];

  for (int c0 = 0; c0 < 512; c0 += 32) {
    // prefetch next c-tile operands (harmless overrun on last iteration)
    short8 naq0 = *(const short8*)&qb[(c0 + 32) * 32];
    short8 naq1 = *(const short8*)&qb[(c0 + 32) * 32 + 16];
    short8 nav0 = *(const short8*)&vb[c0 + 32];
    short8 nav1 = *(const short8*)&vb[c0 + 48];

    // ---- chain A ----
    {
      floatx16 s = __builtin_amdgcn_mfma_f32_32x32x16_bf16(aq0, bkA0, z16, 0, 0, 0);
      s = __builtin_amdgcn_mfma_f32_32x32x16_bf16(aq1, bkA1, s, 0, 0, 0);
      unsigned pk0 = cvt_pk_bf16(fast_exp2(s[0]),  fast_exp2(s[1]));
      unsigned pk1 = cvt_pk_bf16(fast_exp2(s[2]),  fast_exp2(s[3]));
      unsigned pk2 = cvt_pk_bf16(fast_exp2(s[4]),  fast_exp2(s[5]));
      unsigned pk3 = cvt_pk_bf16(fast_exp2(s[6]),  fast_exp2(s[7]));
      unsigned pk4 = cvt_pk_bf16(fast_exp2(s[8]),  fast_exp2(s[9]));
      unsigned pk5 = cvt_pk_bf16(fast_exp2(s[10]), fast_exp2(s[11]));
      unsigned pk6 = cvt_pk_bf16(fast_exp2(s[12]), fast_exp2(s[13]));
      unsigned pk7 = cvt_pk_bf16(fast_exp2(s[14]), fast_exp2(s[15]));
      permlane32_swap(pk0, pk2);
      permlane32_swap(pk1, pk3);
      permlane32_swap(pk4, pk6);
      permlane32_swap(pk5, pk7);
      union { uint4 u; short8 s8; } b0, b1;
      b0.u = make_uint4(pk0, pk1, pk2, pk3);
      b1.u = make_uint4(pk4, pk5, pk6, pk7);
      accA = __builtin_amdgcn_mfma_f32_32x32x16_bf16(av0, b0.s8, accA, 0, 0, 0);
      accA = __builtin_amdgcn_mfma_f32_32x32x16_bf16(av1, b1.s8, accA, 0, 0, 0);
    }
    // ---- chain B ----
    {
      floatx16 s = __builtin_amdgcn_mfma_f32_32x32x16_bf16(aq0, bkB0, z16, 0, 0, 0);
      s = __builtin_amdgcn_mfma_f32_32x32x16_bf16(aq1, bkB1, s, 0, 0, 0);
      unsigned pk0 = cvt_pk_bf16(fast_exp2(s[0]),  fast_exp2(s[1]));
      unsigned pk1 = cvt_pk_bf16(fast_exp2(s[2]),  fast_exp2(s[3]));
      unsigned pk2 = cvt_pk_bf16(fast_exp2(s[4]),  fast_exp2(s[5]));
      unsigned pk3 = cvt_pk_bf16(fast_exp2(s[6]),  fast_exp2(s[7]));
      unsigned pk4 = cvt_pk_bf16(fast_exp2(s[8]),  fast_exp2(s[9]));
      unsigned pk5 = cvt_pk_bf16(fast_exp2(s[10]), fast_exp2(s[11]));
      unsigned pk6 = cvt_pk_bf16(fast_exp2(s[12]), fast_exp2(s[13]));
      unsigned pk7 = cvt_pk_bf16(fast_exp2(s[14]), fast_exp2(s[15]));
      permlane32_swap(pk0, pk2);
      permlane32_swap(pk1, pk3);
      permlane32_swap(pk4, pk6);
      permlane32_swap(pk5, pk7);
      union { uint4 u; short8 s8; } b0, b1;
      b0.u = make_uint4(pk0, pk1, pk2, pk3);
      b1.u = make_uint4(pk4, pk5, pk6, pk7);
      accB = __builtin_amdgcn_mfma_f32_32x32x16_bf16(av0, b0.s8, accB, 0, 0, 0);
      accB = __builtin_amdgcn_mfma_f32_32x32x16_bf16(av1, b1.s8, accB, 0, 0, 0);
    }
    aq0 = naq0; aq1 = naq1; av0 = nav0; av1 = nav1;
  }

  // acc: col=j=l31, row=d=(reg&3)+8*(reg>>2)+4h -> att_t[hw][128]
  unsigned short* orowA = att_t + cpart * 2097152 +
                          (nn * 2048 + jA + l31) * 128 + bh * 32 + 4 * h;
  unsigned short* orowB = att_t + cpart * 2097152 +
                          (nn * 2048 + jB + l31) * 128 + bh * 32 + 4 * h;
  #pragma unroll
  for (int q = 0; q < 4; ++q) {
    uint2 uA = {cvt_pk_bf16(accA[4 * q], accA[4 * q + 1]),
                cvt_pk_bf16(accA[4 * q + 2], accA[4 * q + 3])};
    *(uint2*)&orowA[q * 8] = uA;
    uint2 uB = {cvt_pk_bf16(accB[4 * q], accB[4 * q + 1]),
                cvt_pk_bf16(accB[4 * q + 2], accB[4 * q + 3])};
    *(uint2*)&orowB[q * 8] = uB;
  }
}

// ---------------------------------------------------------------------------
// gemm_out: y = w_g @ (sum of 4 att parts) + out_b via K=512 MFMA; ybuf bf16 +
// GroupNorm partials. grid 512 (p-slab 32, 2 blocks/CU), block 256
// ---------------------------------------------------------------------------
__global__ __launch_bounds__(256) void gemm_out(
    const unsigned short* __restrict__ w_g, const unsigned short* __restrict__ att_t,
    const float* __restrict__ out_b, unsigned short* __restrict__ ybuf_bf,
    float* __restrict__ part) {
  const int wave = threadIdx.x >> 6, lane = threadIdx.x & 63;
  const int lr = lane & 15, g = lane >> 4;
  const int p0 = blockIdx.x * 32;
  const int o0 = wave * 32;
  const floatx4 zero = {0.f, 0.f, 0.f, 0.f};

  short8 a[2][4];
  #pragma unroll
  for (int mf = 0; mf < 2; ++mf)
    #pragma unroll
    for (int kk = 0; kk < 4; ++kk)
      a[mf][kk] = *(const short8*)&w_g[(o0 + mf * 16 + lr) * 128 + kk * 32 + g * 8];

  floatx4 acc[2][2];
  #pragma unroll
  for (int mf = 0; mf < 2; ++mf)
    #pragma unroll
    for (int nf = 0; nf < 2; ++nf) acc[mf][nf] = zero;

  #pragma unroll
  for (int ks = 0; ks < 16; ++ks) {
    const unsigned short* att = att_t + (ks >> 2) * 2097152;
    const int kk = ks & 3;
    #pragma unroll
    for (int nf = 0; nf < 2; ++nf) {
      short8 b = *(const short8*)&att[(p0 + nf * 16 + lr) * 128 + kk * 32 + g * 8];
      acc[0][nf] = __builtin_amdgcn_mfma_f32_16x16x32_bf16(a[0][kk], b, acc[0][nf], 0, 0, 0);
      acc[1][nf] = __builtin_amdgcn_mfma_f32_16x16x32_bf16(a[1][kk], b, acc[1][nf], 0, 0, 0);
    }
  }

  float sg[2] = {0.f, 0.f}, ssg[2] = {0.f, 0.f};
  #pragma unroll
  for (int mf = 0; mf < 2; ++mf) {
    #pragma unroll
    for (int nf = 0; nf < 2; ++nf) {
      #pragma unroll
      for (int r = 0; r < 4; ++r) {
        const int o = o0 + mf * 16 + g * 4 + r;
        float y = acc[mf][nf][r] + out_b[o];
        ybuf_bf[o * HW + p0 + nf * 16 + lr] = f2bf(y);
        sg[mf] += y;
        ssg[mf] += y * y;
      }
    }
  }
  #pragma unroll
  for (int mf = 0; mf < 2; ++mf) {
    float a1 = sg[mf], a2 = ssg[mf];
    #pragma unroll
    for (int st = 1; st < 64; st <<= 1) {
      a1 += __shfl_xor(a1, st);
      a2 += __shfl_xor(a2, st);
    }
    if (lane == 0) {
      part[(blockIdx.x * 8 + wave * 2 + mf) * 2 + 0] = a1;
      part[(blockIdx.x * 8 + wave * 2 + mf) * 2 + 1] = a2;
    }
  }
}

// ---------------------------------------------------------------------------
// gn_finalize: reduce 512 p-block partials per group. grid 8, block 512
// ---------------------------------------------------------------------------
__global__ __launch_bounds__(512) void gn_finalize(
    const float* __restrict__ part, float* __restrict__ stat) {
  const int gg = blockIdx.x;
  const int t = threadIdx.x;
  __shared__ float r1[512], r2[512];
  r1[t] = part[(t * 8 + gg) * 2 + 0];
  r2[t] = part[(t * 8 + gg) * 2 + 1];
  __syncthreads();
  for (int st = 256; st > 0; st >>= 1) {
    if (t < st) { r1[t] += r1[t + st]; r2[t] += r2[t + st]; }
    __syncthreads();
  }
  if (t == 0) {
    const float inv_n = 1.f / (16.f * HW);
    float mu = r1[0] * inv_n;
    float var = r2[0] * inv_n - mu * mu;
    stat[gg * 2 + 0] = mu;
    stat[gg * 2 + 1] = rsqrtf(var + 1e-5f);
  }
}

// ---------------------------------------------------------------------------
// gn_apply: out = (y - mu) * rs * gn_w + gn_b, reading bf16 y. grid 1024
// ---------------------------------------------------------------------------
__global__ __launch_bounds__(256) void gn_apply(
    const unsigned short* __restrict__ ybuf_bf, const float* __restrict__ stat,
    const float* __restrict__ gn_w, const float* __restrict__ gn_b,
    float* __restrict__ outp) {
  const int i = (blockIdx.x * 256 + threadIdx.x) * 8;
  const int ch = i >> 14;
  const int g = ch >> 4;
  float mu = stat[g * 2], rs = stat[g * 2 + 1];
  float w = gn_w[ch] * rs;
  float b = gn_b[ch] - mu * w;
  short8 v = *(const short8*)&ybuf_bf[i];
  float4 r0 = {bf2f((unsigned short)v[0]) * w + b, bf2f((unsigned short)v[1]) * w + b,
               bf2f((unsigned short)v[2]) * w + b, bf2f((unsigned short)v[3]) * w + b};
  float4 r1 = {bf2f((unsigned short)v[4]) * w + b, bf2f((unsigned short)v[5]) * w + b,
               bf2f((unsigned short)v[6]) * w + b, bf2f((unsigned short)v[7]) * w + b};
  *(float4*)&outp[i] = r0;
  *(float4*)&outp[i + 4] = r1;
}

// ---------------------------------------------------------------------------
extern "C" void kernel_launch(void* const* d_in, const int* in_sizes, int n_in,
                              void* d_out, int out_size, void* d_ws, size_t ws_size,
                              hipStream_t stream) {
  const float* x     = (const float*)d_in[0];
  const float* w_qkv = (const float*)d_in[1];
  const float* se_w1 = (const float*)d_in[2];
  const float* se_b1 = (const float*)d_in[3];
  const float* se_w2 = (const float*)d_in[4];
  const float* se_b2 = (const float*)d_in[5];
  const float* out_w = (const float*)d_in[6];
  const float* out_b = (const float*)d_in[7];
  const float* gn_w  = (const float*)d_in[8];
  const float* gn_b  = (const float*)d_in[9];
  float* out = (float*)d_out;

  float* ws = (float*)d_ws;
  float* zpart  = ws;                        // 4*65536 f
  float* part_v = zpart + 262144;            // 65536 f
  float* part   = part_v + 65536;            // 8192 f
  float* stat   = part + 8192;               // 16 f
  unsigned short* w_bf    = (unsigned short*)(stat + 16);  // 49152 sh
  unsigned short* x_t     = w_bf + 49152;                  // 2097152 sh
  unsigned short* q_t     = x_t + 2097152;                 // 2097152 sh
  unsigned short* k_t     = q_t + 2097152;                 // 2097152 sh
  unsigned short* v_bf    = k_t + 2097152;                 // 2097152 sh
  unsigned short* vz      = v_bf + 2097152;                // 2097152 sh
  unsigned short* w_g     = vz + 2097152;                  // 16384 sh
  unsigned short* att_t   = w_g + 16384;                   // 4*2097152 sh
  unsigned short* ybuf_bf = att_t + 8388608;               // 2097152 sh

  cast_wx<<<304, 256, 0, stream>>>(w_qkv, x, w_bf, x_t);
  gemm_qkv<<<512, 512, 0, stream>>>(w_bf, x_t, q_t, k_t, v_bf, part_v);
  se_mlp<<<1, 128, 0, stream>>>(part_v, se_w1, se_b1, se_w2, se_b2, out_w, w_g);
  attn_stats_mfma<<<2048, 256, 0, stream>>>(q_t, k_t, zpart);
  vz_cast<<<1024, 256, 0, stream>>>(v_bf, zpart, vz);
  attn_apply_mfma<<<1024, 256, 0, stream>>>(q_t, k_t, vz, att_t);
  gemm_out<<<512, 256, 0, stream>>>(w_g, att_t, out_b, ybuf_bf, part);
  gn_finalize<<<8, 512, 0, stream>>>(part, stat);
  gn_apply<<<1024, 256, 0, stream>>>(ybuf_bf, stat, gn_w, gn_b, out);
}

// Round 15
// 109.434 us; speedup vs baseline: 1.0548x; 1.0548x over previous
//
#include <hip/hip_runtime.h>
#include <hip/hip_bf16.h>

#define HW 16384
// (1/sqrt(32)) * log2(e): folded into q weights so exp(S) == exp2(S')
#define QSCALE (0.17677669529663687f * 1.4426950408889634f)

typedef __attribute__((ext_vector_type(8))) short short8;
typedef __attribute__((ext_vector_type(4))) float floatx4;
typedef __attribute__((ext_vector_type(16))) float floatx16;

// HW packed convert: lo = bf16(a), hi = bf16(b)  (RNE on gfx950)
__device__ inline unsigned cvt_pk_bf16(float a, float b) {
  unsigned r;
  asm("v_cvt_pk_bf16_f32 %0, %1, %2" : "=v"(r) : "v"(a), "v"(b));
  return r;
}
__device__ inline unsigned short f2bf(float a) {
  return (unsigned short)(cvt_pk_bf16(a, 0.f) & 0xffff);
}
__device__ inline float bf2f(unsigned short u) {
  union { unsigned u; float f; } c;
  c.u = (unsigned)u << 16;
  return c.f;
}
// exchange: a.hi32lanes <-> b.lo32lanes (both registers updated)
__device__ inline void permlane32_swap(unsigned& a, unsigned& b) {
  asm("v_permlane32_swap_b32 %0, %1" : "+v"(a), "+v"(b));
}
// bare v_exp_f32 (no OCML over/underflow fixup; exact for |x| < 126)
__device__ inline float fast_exp2(float x) {
  return __builtin_amdgcn_exp2f(x);
}

// ---------------------------------------------------------------------------
// cast_wx: blocks 0..255 transpose x f32 [128][HW] -> x_t bf16 [HW][128];
// blocks 256..303 cast w_qkv f32 [384][128] -> bf16 (q rows scaled by QSCALE)
// ---------------------------------------------------------------------------
__global__ __launch_bounds__(256) void cast_wx(
    const float* __restrict__ w, const float* __restrict__ x,
    unsigned short* __restrict__ w_bf, unsigned short* __restrict__ x_t) {
  __shared__ float tile[128][65];
  const int t = threadIdx.x;
  if (blockIdx.x >= 256) {
    const int i4 = ((blockIdx.x - 256) * 256 + t) * 4;
    const int o = i4 >> 7;
    const float sc = (o < 128) ? QSCALE : 1.f;
    float4 v = *(const float4*)&w[i4];
    uint2 u = {cvt_pk_bf16(v.x * sc, v.y * sc), cvt_pk_bf16(v.z * sc, v.w * sc)};
    *(uint2*)&w_bf[i4] = u;
    return;
  }
  const int p0 = blockIdx.x * 64;
  #pragma unroll
  for (int i = 0; i < 32; ++i) {
    int idx = t + i * 256;
    int c = idx >> 6, p = idx & 63;
    tile[c][p] = x[c * HW + p0 + p];
  }
  __syncthreads();
  const int p = t >> 2, q = t & 3;
  unsigned u[16];
  #pragma unroll
  for (int i = 0; i < 16; ++i)
    u[i] = cvt_pk_bf16(tile[q * 32 + 2 * i][p], tile[q * 32 + 2 * i + 1][p]);
  unsigned short* dst = &x_t[(p0 + p) * 128 + q * 32];
  #pragma unroll
  for (int i = 0; i < 4; ++i) *(uint4*)&dst[i * 8] = *(const uint4*)&u[i * 4];
}

// ---------------------------------------------------------------------------
// gemm_qkv: MFMA bf16, one block = all 384 o-rows x 64-p slab.
// q -> q_t bf16 [bn][c][32] (QSCALE folded), k -> k_t, v -> v_bf [128][HW].
// Epilogue: per-block v row-sums -> part_v[block][128] (feeds SE mean).
// grid 256, block 512 (8 waves x 48 o-rows)
// ---------------------------------------------------------------------------
__global__ __launch_bounds__(512) void gemm_qkv(
    const unsigned short* __restrict__ w_bf, const unsigned short* __restrict__ x_t,
    unsigned short* __restrict__ q_t, unsigned short* __restrict__ k_t,
    unsigned short* __restrict__ v_bf, float* __restrict__ part_v) {
  const int wave = threadIdx.x >> 6, lane = threadIdx.x & 63;
  const int lr = lane & 15, g = lane >> 4;
  const int p0 = blockIdx.x * 64;
  const int ow = wave * 48;
  const floatx4 zero = {0.f, 0.f, 0.f, 0.f};

  short8 a[3][4];
  #pragma unroll
  for (int mf = 0; mf < 3; ++mf)
    #pragma unroll
    for (int kk = 0; kk < 4; ++kk)
      a[mf][kk] = *(const short8*)&w_bf[(ow + mf * 16 + lr) * 128 + kk * 32 + g * 8];

  floatx4 acc[3][4];
  #pragma unroll
  for (int mf = 0; mf < 3; ++mf)
    #pragma unroll
    for (int nf = 0; nf < 4; ++nf) acc[mf][nf] = zero;

  #pragma unroll
  for (int kk = 0; kk < 4; ++kk) {
    #pragma unroll
    for (int nf = 0; nf < 4; ++nf) {
      short8 b = *(const short8*)&x_t[(p0 + nf * 16 + lr) * 128 + kk * 32 + g * 8];
      #pragma unroll
      for (int mf = 0; mf < 3; ++mf)
        acc[mf][nf] = __builtin_amdgcn_mfma_f32_16x16x32_bf16(a[mf][kk], b, acc[mf][nf], 0, 0, 0);
    }
  }

  float vsum[3][4];
  #pragma unroll
  for (int mf = 0; mf < 3; ++mf)
    #pragma unroll
    for (int rr = 0; rr < 4; ++rr) vsum[mf][rr] = 0.f;

  #pragma unroll
  for (int mf = 0; mf < 3; ++mf) {
    const int ob = ow + mf * 16;
    #pragma unroll
    for (int nf = 0; nf < 4; ++nf) {
      const int p = p0 + nf * 16 + lr;
      const int c = p & 2047, nn = p >> 11;
      floatx4 r = acc[mf][nf];
      if (ob < 128) {
        const int bh = ob >> 5, d0 = (ob & 31) + g * 4;
        uint2 u = {cvt_pk_bf16(r[0], r[1]), cvt_pk_bf16(r[2], r[3])};
        *(uint2*)&q_t[((bh * 8 + nn) * 2048 + c) * 32 + d0] = u;
      } else if (ob < 256) {
        const int oo = ob - 128, bh = oo >> 5, d0 = (oo & 31) + g * 4;
        uint2 u = {cvt_pk_bf16(r[0], r[1]), cvt_pk_bf16(r[2], r[3])};
        *(uint2*)&k_t[((bh * 8 + nn) * 2048 + c) * 32 + d0] = u;
      } else {
        const int d = ob - 256 + g * 4;
        #pragma unroll
        for (int rr = 0; rr < 4; ++rr) {
          v_bf[(d + rr) * HW + p] = f2bf(r[rr]);
          vsum[mf][rr] += r[rr];
        }
      }
    }
  }
  // v row-sum partials: reduce over the 16 p-lanes (lr), write per-block
  #pragma unroll
  for (int mf = 0; mf < 3; ++mf) {
    const int ob = ow + mf * 16;
    if (ob >= 256) {
      #pragma unroll
      for (int rr = 0; rr < 4; ++rr) {
        float vv = vsum[mf][rr];
        vv += __shfl_xor(vv, 1); vv += __shfl_xor(vv, 2);
        vv += __shfl_xor(vv, 4); vv += __shfl_xor(vv, 8);
        if (lr == 0)
          part_v[blockIdx.x * 128 + (ob - 256) + g * 4 + rr] = vv;
      }
    }
  }
}

// ---------------------------------------------------------------------------
// se_mlp: reduce part_v -> mean(v) = SE input; gate g; w_g = out_w * g (bf16)
// (softmax rows sum to 1 => mean over hw of attn_out == mean of v)
// ---------------------------------------------------------------------------
__global__ __launch_bounds__(128) void se_mlp(
    const float* __restrict__ part_v, const float* __restrict__ w1,
    const float* __restrict__ b1, const float* __restrict__ w2,
    const float* __restrict__ b2, const float* __restrict__ out_w,
    unsigned short* __restrict__ w_g) {
  __shared__ float s_sh[128], s1_sh[32], g_sh[128];
  const int t = threadIdx.x;
  float a0 = 0.f;
  for (int b = 0; b < 256; ++b) a0 += part_v[b * 128 + t];
  s_sh[t] = a0 * (1.f / HW);
  __syncthreads();
  if (t < 32) {
    float a = b1[t];
    for (int c = 0; c < 128; ++c) a += w1[t * 128 + c] * s_sh[c];
    s1_sh[t] = a / (1.f + __expf(-a));
  }
  __syncthreads();
  {
    float a = b2[t];
    for (int i = 0; i < 32; ++i) a += w2[t * 32 + i] * s1_sh[i];
    g_sh[t] = 1.f / (1.f + __expf(-a));
  }
  __syncthreads();
  for (int o = 0; o < 128; ++o) w_g[o * 128 + t] = f2bf(out_w[o * 128 + t] * g_sh[t]);
}

// ---------------------------------------------------------------------------
// Pass A: Z partials via 32x32x16 MFMA, TWO independent e-tile chains +
// register-prefetched k loads, e split in 4 parts.
// grid 2048 flat (f&7 -> bn%8, XCD-pinned), block 256 (4 waves x 32 c)
// ---------------------------------------------------------------------------
__global__ __launch_bounds__(256, 4) void attn_stats_mfma(
    const unsigned short* __restrict__ q_t, const unsigned short* __restrict__ k_t,
    float* __restrict__ zpart) {
  const int wave = threadIdx.x >> 6, lane = threadIdx.x & 63;
  const int f = blockIdx.x;
  const int bn = ((f >> 7) & 3) * 8 + (f & 7);
  const int ct = (f >> 3) & 15;
  const int epart = f >> 9;  // 0..3
  const int l31 = lane & 31, h = lane >> 5;
  const int c0 = ct * 128 + wave * 32;
  const floatx16 z16 = {0.f,0.f,0.f,0.f,0.f,0.f,0.f,0.f,
                        0.f,0.f,0.f,0.f,0.f,0.f,0.f,0.f};

  const unsigned short* qp = &q_t[(bn * 2048 + c0 + l31) * 32 + h * 8];
  short8 aq0 = *(const short8*)qp;
  short8 aq1 = *(const short8*)(qp + 16);

  float z[16] = {};
  const unsigned short* kb = &k_t[(bn * 2048 + epart * 512 + l31) * 32 + h * 8];

  short8 b0a = *(const short8*)&kb[0];
  short8 b0b = *(const short8*)&kb[16];
  short8 b1a = *(const short8*)&kb[32 * 32];
  short8 b1b = *(const short8*)&kb[32 * 32 + 16];

  for (int e0 = 0; e0 < 512; e0 += 64) {
    // prefetch next 64-e pair (harmless overrun on last iteration)
    const unsigned short* nk = &kb[(e0 + 64) * 32];
    short8 nb0a = *(const short8*)&nk[0];
    short8 nb0b = *(const short8*)&nk[16];
    short8 nb1a = *(const short8*)&nk[32 * 32];
    short8 nb1b = *(const short8*)&nk[32 * 32 + 16];

    floatx16 s1 = __builtin_amdgcn_mfma_f32_32x32x16_bf16(aq0, b0a, z16, 0, 0, 0);
    s1 = __builtin_amdgcn_mfma_f32_32x32x16_bf16(aq1, b0b, s1, 0, 0, 0);
    floatx16 s2 = __builtin_amdgcn_mfma_f32_32x32x16_bf16(aq0, b1a, z16, 0, 0, 0);
    s2 = __builtin_amdgcn_mfma_f32_32x32x16_bf16(aq1, b1b, s2, 0, 0, 0);
    #pragma unroll
    for (int r = 0; r < 16; ++r) z[r] += fast_exp2(s1[r]) + fast_exp2(s2[r]);

    b0a = nb0a; b0b = nb0b; b1a = nb1a; b1b = nb1b;
  }
  #pragma unroll
  for (int r = 0; r < 16; ++r) {
    float v = z[r];
    v += __shfl_xor(v, 1); v += __shfl_xor(v, 2); v += __shfl_xor(v, 4);
    v += __shfl_xor(v, 8); v += __shfl_xor(v, 16);
    z[r] = v;
  }
  if (l31 == 0) {
    #pragma unroll
    for (int r = 0; r < 16; ++r)
      zpart[epart * 65536 + bn * 2048 + c0 + (r & 3) + 8 * (r >> 2) + 4 * h] = z[r];
  }
}

// ---------------------------------------------------------------------------
// vz = v / sum(4 z parts), bf16 [d][hw].  grid 1024, block 256, 8 elts/thread
// ---------------------------------------------------------------------------
__global__ __launch_bounds__(256) void vz_cast(
    const unsigned short* __restrict__ v_bf, const float* __restrict__ zpart,
    unsigned short* __restrict__ vz) {
  const int idx = (blockIdx.x * 256 + threadIdx.x) * 8;
  const int row = idx >> 14, p = idx & 16383;
  const int bh = row >> 5, nn = p >> 11, c = p & 2047;
  short8 v8 = *(const short8*)&v_bf[idx];
  const int zb = (bh * 8 + nn) * 2048 + c;
  float zs[8];
  #pragma unroll
  for (int i = 0; i < 8; ++i)
    zs[i] = __builtin_amdgcn_rcpf((zpart[zb + i] + zpart[65536 + zb + i]) +
                                  (zpart[131072 + zb + i] + zpart[196608 + zb + i]));
  unsigned u[4];
  #pragma unroll
  for (int i = 0; i < 4; ++i)
    u[i] = cvt_pk_bf16(bf2f((unsigned short)v8[2 * i]) * zs[2 * i],
                       bf2f((unsigned short)v8[2 * i + 1]) * zs[2 * i + 1]);
  uint4 o = {u[0], u[1], u[2], u[3]};
  *(uint4*)&vz[idx] = o;
}

// ---------------------------------------------------------------------------
// Pass B: PV via 32x32x16 MFMA. Wave owns TWO j-tiles (independent chains,
// shared aq/av loads) + register double-buffered prefetch; c split in 4.
// P handed QK->PV in-register via v_permlane32_swap. No LDS, no barriers.
// grid 1024 flat (f&7 -> bn%8, XCD-pinned), block 256.
// Output att_t bf16 transposed [hw][128], 4 c-part partials.
// ---------------------------------------------------------------------------
__global__ __launch_bounds__(256, 4) void attn_apply_mfma(
    const unsigned short* __restrict__ q_t, const unsigned short* __restrict__ k_t,
    const unsigned short* __restrict__ vz, unsigned short* __restrict__ att_t) {
  const int wave = threadIdx.x >> 6, lane = threadIdx.x & 63;
  const int f = blockIdx.x;
  const int bn = ((f >> 6) & 3) * 8 + (f & 7);
  const int jg = (f >> 3) & 7;
  const int cpart = f >> 8;  // 0..3
  const int bh = bn >> 3, nn = bn & 7;
  const int jA = jg * 256 + wave * 64;
  const int jB = jA + 32;
  const int l31 = lane & 31, h = lane >> 5;
  const floatx16 z16 = {0.f,0.f,0.f,0.f,0.f,0.f,0.f,0.f,
                        0.f,0.f,0.f,0.f,0.f,0.f,0.f,0.f};

  const unsigned short* kpA = &k_t[(bn * 2048 + jA + l31) * 32 + h * 8];
  const unsigned short* kpB = &k_t[(bn * 2048 + jB + l31) * 32 + h * 8];
  short8 bkA0 = *(const short8*)kpA, bkA1 = *(const short8*)(kpA + 16);
  short8 bkB0 = *(const short8*)kpB, bkB1 = *(const short8*)(kpB + 16);

  floatx16 accA = z16, accB = z16;
  const unsigned short* qb = &q_t[(bn * 2048 + cpart * 512 + l31) * 32 + h * 8];
  const unsigned short* vb = &vz[(bh * 32 + l31) * HW + nn * 2048 + cpart * 512 + h * 8];

  short8 aq0 = *(const short8*)&qb[0];
  short8 aq1 = *(const short8*)&qb[16];
  short8 av0 = *(const short8*)&vb[0];
  short8 av1 = *(const short8*)&vb[16];

  for (int c0 = 0; c0 < 512; c0 += 32) {
    // prefetch next c-tile operands (harmless overrun on last iteration)
    short8 naq0 = *(const short8*)&qb[(c0 + 32) * 32];
    short8 naq1 = *(const short8*)&qb[(c0 + 32) * 32 + 16];
    short8 nav0 = *(const short8*)&vb[c0 + 32];
    short8 nav1 = *(const short8*)&vb[c0 + 48];

    // ---- chain A ----
    {
      floatx16 s = __builtin_amdgcn_mfma_f32_32x32x16_bf16(aq0, bkA0, z16, 0, 0, 0);
      s = __builtin_amdgcn_mfma_f32_32x32x16_bf16(aq1, bkA1, s, 0, 0, 0);
      unsigned pk0 = cvt_pk_bf16(fast_exp2(s[0]),  fast_exp2(s[1]));
      unsigned pk1 = cvt_pk_bf16(fast_exp2(s[2]),  fast_exp2(s[3]));
      unsigned pk2 = cvt_pk_bf16(fast_exp2(s[4]),  fast_exp2(s[5]));
      unsigned pk3 = cvt_pk_bf16(fast_exp2(s[6]),  fast_exp2(s[7]));
      unsigned pk4 = cvt_pk_bf16(fast_exp2(s[8]),  fast_exp2(s[9]));
      unsigned pk5 = cvt_pk_bf16(fast_exp2(s[10]), fast_exp2(s[11]));
      unsigned pk6 = cvt_pk_bf16(fast_exp2(s[12]), fast_exp2(s[13]));
      unsigned pk7 = cvt_pk_bf16(fast_exp2(s[14]), fast_exp2(s[15]));
      permlane32_swap(pk0, pk2);
      permlane32_swap(pk1, pk3);
      permlane32_swap(pk4, pk6);
      permlane32_swap(pk5, pk7);
      union { uint4 u; short8 s8; } b0, b1;
      b0.u = make_uint4(pk0, pk1, pk2, pk3);
      b1.u = make_uint4(pk4, pk5, pk6, pk7);
      accA = __builtin_amdgcn_mfma_f32_32x32x16_bf16(av0, b0.s8, accA, 0, 0, 0);
      accA = __builtin_amdgcn_mfma_f32_32x32x16_bf16(av1, b1.s8, accA, 0, 0, 0);
    }
    // ---- chain B ----
    {
      floatx16 s = __builtin_amdgcn_mfma_f32_32x32x16_bf16(aq0, bkB0, z16, 0, 0, 0);
      s = __builtin_amdgcn_mfma_f32_32x32x16_bf16(aq1, bkB1, s, 0, 0, 0);
      unsigned pk0 = cvt_pk_bf16(fast_exp2(s[0]),  fast_exp2(s[1]));
      unsigned pk1 = cvt_pk_bf16(fast_exp2(s[2]),  fast_exp2(s[3]));
      unsigned pk2 = cvt_pk_bf16(fast_exp2(s[4]),  fast_exp2(s[5]));
      unsigned pk3 = cvt_pk_bf16(fast_exp2(s[6]),  fast_exp2(s[7]));
      unsigned pk4 = cvt_pk_bf16(fast_exp2(s[8]),  fast_exp2(s[9]));
      unsigned pk5 = cvt_pk_bf16(fast_exp2(s[10]), fast_exp2(s[11]));
      unsigned pk6 = cvt_pk_bf16(fast_exp2(s[12]), fast_exp2(s[13]));
      unsigned pk7 = cvt_pk_bf16(fast_exp2(s[14]), fast_exp2(s[15]));
      permlane32_swap(pk0, pk2);
      permlane32_swap(pk1, pk3);
      permlane32_swap(pk4, pk6);
      permlane32_swap(pk5, pk7);
      union { uint4 u; short8 s8; } b0, b1;
      b0.u = make_uint4(pk0, pk1, pk2, pk3);
      b1.u = make_uint4(pk4, pk5, pk6, pk7);
      accB = __builtin_amdgcn_mfma_f32_32x32x16_bf16(av0, b0.s8, accB, 0, 0, 0);
      accB = __builtin_amdgcn_mfma_f32_32x32x16_bf16(av1, b1.s8, accB, 0, 0, 0);
    }
    aq0 = naq0; aq1 = naq1; av0 = nav0; av1 = nav1;
  }

  // acc: col=j=l31, row=d=(reg&3)+8*(reg>>2)+4h -> att_t[hw][128]
  unsigned short* orowA = att_t + cpart * 2097152 +
                          (nn * 2048 + jA + l31) * 128 + bh * 32 + 4 * h;
  unsigned short* orowB = att_t + cpart * 2097152 +
                          (nn * 2048 + jB + l31) * 128 + bh * 32 + 4 * h;
  #pragma unroll
  for (int q = 0; q < 4; ++q) {
    uint2 uA = {cvt_pk_bf16(accA[4 * q], accA[4 * q + 1]),
                cvt_pk_bf16(accA[4 * q + 2], accA[4 * q + 3])};
    *(uint2*)&orowA[q * 8] = uA;
    uint2 uB = {cvt_pk_bf16(accB[4 * q], accB[4 * q + 1]),
                cvt_pk_bf16(accB[4 * q + 2], accB[4 * q + 3])};
    *(uint2*)&orowB[q * 8] = uB;
  }
}

// ---------------------------------------------------------------------------
// gemm_out: y = w_g @ (sum of 4 att parts) + out_b via K=512 MFMA; ybuf bf16 +
// GroupNorm partials. grid 256 (p-slab 64), block 256 (4 waves x 32 o)
// ---------------------------------------------------------------------------
__global__ __launch_bounds__(256) void gemm_out(
    const unsigned short* __restrict__ w_g, const unsigned short* __restrict__ att_t,
    const float* __restrict__ out_b, unsigned short* __restrict__ ybuf_bf,
    float* __restrict__ part) {
  const int wave = threadIdx.x >> 6, lane = threadIdx.x & 63;
  const int lr = lane & 15, g = lane >> 4;
  const int p0 = blockIdx.x * 64;
  const int o0 = wave * 32;
  const floatx4 zero = {0.f, 0.f, 0.f, 0.f};

  short8 a[2][4];
  #pragma unroll
  for (int mf = 0; mf < 2; ++mf)
    #pragma unroll
    for (int kk = 0; kk < 4; ++kk)
      a[mf][kk] = *(const short8*)&w_g[(o0 + mf * 16 + lr) * 128 + kk * 32 + g * 8];

  floatx4 acc[2][4];
  #pragma unroll
  for (int mf = 0; mf < 2; ++mf)
    #pragma unroll
    for (int nf = 0; nf < 4; ++nf) acc[mf][nf] = zero;

  #pragma unroll
  for (int ks = 0; ks < 16; ++ks) {
    const unsigned short* att = att_t + (ks >> 2) * 2097152;
    const int kk = ks & 3;
    #pragma unroll
    for (int nf = 0; nf < 4; ++nf) {
      short8 b = *(const short8*)&att[(p0 + nf * 16 + lr) * 128 + kk * 32 + g * 8];
      acc[0][nf] = __builtin_amdgcn_mfma_f32_16x16x32_bf16(a[0][kk], b, acc[0][nf], 0, 0, 0);
      acc[1][nf] = __builtin_amdgcn_mfma_f32_16x16x32_bf16(a[1][kk], b, acc[1][nf], 0, 0, 0);
    }
  }

  float sg[2] = {0.f, 0.f}, ssg[2] = {0.f, 0.f};
  #pragma unroll
  for (int mf = 0; mf < 2; ++mf) {
    #pragma unroll
    for (int nf = 0; nf < 4; ++nf) {
      #pragma unroll
      for (int r = 0; r < 4; ++r) {
        const int o = o0 + mf * 16 + g * 4 + r;
        float y = acc[mf][nf][r] + out_b[o];
        ybuf_bf[o * HW + p0 + nf * 16 + lr] = f2bf(y);
        sg[mf] += y;
        ssg[mf] += y * y;
      }
    }
  }
  #pragma unroll
  for (int mf = 0; mf < 2; ++mf) {
    float a1 = sg[mf], a2 = ssg[mf];
    #pragma unroll
    for (int st = 1; st < 64; st <<= 1) {
      a1 += __shfl_xor(a1, st);
      a2 += __shfl_xor(a2, st);
    }
    if (lane == 0) {
      part[(blockIdx.x * 8 + wave * 2 + mf) * 2 + 0] = a1;
      part[(blockIdx.x * 8 + wave * 2 + mf) * 2 + 1] = a2;
    }
  }
}

// ---------------------------------------------------------------------------
// gn_apply: fused finalize+apply. Each block covers exactly one channel's
// 2048-elt slab (16384/2048=8 blocks per channel) -> group is block-constant.
// Block redundantly reduces its group's 256 partials (L2-resident) in LDS,
// then applies the affine. grid 1024, block 256.
// ---------------------------------------------------------------------------
__global__ __launch_bounds__(256) void gn_apply(
    const unsigned short* __restrict__ ybuf_bf, const float* __restrict__ part,
    const float* __restrict__ gn_w, const float* __restrict__ gn_b,
    float* __restrict__ outp) {
  const int i = (blockIdx.x * 256 + threadIdx.x) * 8;
  const int ch = i >> 14;
  const int gg = ch >> 4;
  const int t = threadIdx.x;

  __shared__ float r1[256], r2[256];
  r1[t] = part[(t * 8 + gg) * 2 + 0];
  r2[t] = part[(t * 8 + gg) * 2 + 1];
  __syncthreads();
  for (int st = 128; st > 0; st >>= 1) {
    if (t < st) { r1[t] += r1[t + st]; r2[t] += r2[t + st]; }
    __syncthreads();
  }
  const float inv_n = 1.f / (16.f * HW);
  float mu = r1[0] * inv_n;
  float var = r2[0] * inv_n - mu * mu;
  float rs = rsqrtf(var + 1e-5f);

  float w = gn_w[ch] * rs;
  float b = gn_b[ch] - mu * w;
  short8 v = *(const short8*)&ybuf_bf[i];
  float4 o0 = {bf2f((unsigned short)v[0]) * w + b, bf2f((unsigned short)v[1]) * w + b,
               bf2f((unsigned short)v[2]) * w + b, bf2f((unsigned short)v[3]) * w + b};
  float4 o1 = {bf2f((unsigned short)v[4]) * w + b, bf2f((unsigned short)v[5]) * w + b,
               bf2f((unsigned short)v[6]) * w + b, bf2f((unsigned short)v[7]) * w + b};
  *(float4*)&outp[i] = o0;
  *(float4*)&outp[i + 4] = o1;
}

// ---------------------------------------------------------------------------
extern "C" void kernel_launch(void* const* d_in, const int* in_sizes, int n_in,
                              void* d_out, int out_size, void* d_ws, size_t ws_size,
                              hipStream_t stream) {
  const float* x     = (const float*)d_in[0];
  const float* w_qkv = (const float*)d_in[1];
  const float* se_w1 = (const float*)d_in[2];
  const float* se_b1 = (const float*)d_in[3];
  const float* se_w2 = (const float*)d_in[4];
  const float* se_b2 = (const float*)d_in[5];
  const float* out_w = (const float*)d_in[6];
  const float* out_b = (const float*)d_in[7];
  const float* gn_w  = (const float*)d_in[8];
  const float* gn_b  = (const float*)d_in[9];
  float* out = (float*)d_out;

  float* ws = (float*)d_ws;
  float* zpart  = ws;                        // 4*65536 f
  float* part_v = zpart + 262144;            // 32768 f
  float* part   = part_v + 32768;            // 4096 f
  float* stat   = part + 4096;               // 16 f (unused, kept for layout)
  unsigned short* w_bf    = (unsigned short*)(stat + 16);  // 49152 sh
  unsigned short* x_t     = w_bf + 49152;                  // 2097152 sh
  unsigned short* q_t     = x_t + 2097152;                 // 2097152 sh
  unsigned short* k_t     = q_t + 2097152;                 // 2097152 sh
  unsigned short* v_bf    = k_t + 2097152;                 // 2097152 sh
  unsigned short* vz      = v_bf + 2097152;                // 2097152 sh
  unsigned short* w_g     = vz + 2097152;                  // 16384 sh
  unsigned short* att_t   = w_g + 16384;                   // 4*2097152 sh
  unsigned short* ybuf_bf = att_t + 8388608;               // 2097152 sh

  cast_wx<<<304, 256, 0, stream>>>(w_qkv, x, w_bf, x_t);
  gemm_qkv<<<256, 512, 0, stream>>>(w_bf, x_t, q_t, k_t, v_bf, part_v);
  se_mlp<<<1, 128, 0, stream>>>(part_v, se_w1, se_b1, se_w2, se_b2, out_w, w_g);
  attn_stats_mfma<<<2048, 256, 0, stream>>>(q_t, k_t, zpart);
  vz_cast<<<1024, 256, 0, stream>>>(v_bf, zpart, vz);
  attn_apply_mfma<<<1024, 256, 0, stream>>>(q_t, k_t, vz, att_t);
  gemm_out<<<256, 256, 0, stream>>>(w_g, att_t, out_b, ybuf_bf, part);
  gn_apply<<<1024, 256, 0, stream>>>(ybuf_bf, part, gn_w, gn_b, out);
}